// Round 1
// baseline (386.004 us; speedup 1.0000x reference)
//
#include <hip/hip_runtime.h>
#include <math.h>

// Problem constants (fixed by reference setup_inputs)
constexpr int CIN  = 256;
constexpr int NST  = 512;          // N
constexpr int LSEQ = 4096;
constexpr int BB   = 4;
constexpr int ROWS = BB * LSEQ;    // 16384
constexpr int COUT = 256;
constexpr int LC   = 64;           // scan chunk length
constexpr int NC   = LSEQ / LC;    // 64 chunks per batch

// ---------------------------------------------------------------------------
// Kernel 1: fused projection GEMM + elementwise epilogue.
// Computes, for each row r (= b*L+l) and state n:
//   xp = x@Wx+bx ; bm = x@Wbc[:, :N]+bbc[:N] ; c = x@Wbc[:, N:]+bbc[N:] ;
//   d  = x@Wd+bd
//   A  = 1/(1+exp(d))   (== exp(-softplus(d)))
//   u  = (1-A)*bm*xp    (== B_bar * x_proj)
// Stores A, u, c as [ROWS, NST] fp32 in workspace.
// Block: 256 threads (16 n-groups x 16 row-groups). Tile: 64 rows x 64 n x 4 mats.
// Each thread: 4 rows x 4 n x 4 mats = 64 fp32 accumulators.
// ---------------------------------------------------------------------------
__global__ __launch_bounds__(256, 4)
void proj_kernel(const float* __restrict__ x,
                 const float* __restrict__ Wx,  const float* __restrict__ bx,
                 const float* __restrict__ Wbc, const float* __restrict__ bbc,
                 const float* __restrict__ Wd,  const float* __restrict__ bd,
                 float* __restrict__ Aarr, float* __restrict__ Uarr,
                 float* __restrict__ Carr)
{
    constexpr int KT = 16;
    __shared__ alignas(16) float xs [KT][64];
    __shared__ alignas(16) float wxs[KT][64];
    __shared__ alignas(16) float wbs[KT][64];
    __shared__ alignas(16) float wcs[KT][64];
    __shared__ alignas(16) float wds[KT][64];

    const int tid  = threadIdx.x;
    const int tx   = tid & 15;        // n group   (tx*4 .. tx*4+3)
    const int ty   = tid >> 4;        // row group (ty*4 .. ty*4+3)
    const int row0 = blockIdx.x * 64;
    const int n0   = blockIdx.y * 64;

    float ax[4][4] = {{0}}, ab[4][4] = {{0}}, ac[4][4] = {{0}}, ad[4][4] = {{0}};

    // staging-load index helpers
    const int lrow = tid >> 2;        // 0..63 : row within tile (x staging)
    const int lkq  = tid & 3;         // 0..3  : k quad          (x staging)
    const int wk   = tid >> 4;        // 0..15 : k within tile   (w staging)
    const int wn4  = tid & 15;        // 0..15 : n quad          (w staging)

    for (int k0 = 0; k0 < CIN; k0 += KT) {
        // global loads into registers first
        float4 xv  = *(const float4*)&x  [(size_t)(row0 + lrow) * CIN + k0 + lkq * 4];
        float4 wxv = *(const float4*)&Wx [(size_t)(k0 + wk) * NST      + n0 + wn4 * 4];
        float4 wbv = *(const float4*)&Wbc[(size_t)(k0 + wk) * (2*NST)  + n0 + wn4 * 4];
        float4 wcv = *(const float4*)&Wbc[(size_t)(k0 + wk) * (2*NST)  + NST + n0 + wn4 * 4];
        float4 wdv = *(const float4*)&Wd [(size_t)(k0 + wk) * NST      + n0 + wn4 * 4];

        __syncthreads();   // previous iteration's LDS reads must finish
        // x tile transposed into xs[k][row]
        xs[lkq*4 + 0][lrow] = xv.x;
        xs[lkq*4 + 1][lrow] = xv.y;
        xs[lkq*4 + 2][lrow] = xv.z;
        xs[lkq*4 + 3][lrow] = xv.w;
        *(float4*)&wxs[wk][wn4*4] = wxv;
        *(float4*)&wbs[wk][wn4*4] = wbv;
        *(float4*)&wcs[wk][wn4*4] = wcv;
        *(float4*)&wds[wk][wn4*4] = wdv;
        __syncthreads();

        #pragma unroll
        for (int kk = 0; kk < KT; ++kk) {
            float xr[4], wxr[4], wbr[4], wcr[4], wdr[4];
            *(float4*)xr  = *(const float4*)&xs [kk][ty*4];
            *(float4*)wxr = *(const float4*)&wxs[kk][tx*4];
            *(float4*)wbr = *(const float4*)&wbs[kk][tx*4];
            *(float4*)wcr = *(const float4*)&wcs[kk][tx*4];
            *(float4*)wdr = *(const float4*)&wds[kk][tx*4];
            #pragma unroll
            for (int i = 0; i < 4; ++i) {
                #pragma unroll
                for (int j = 0; j < 4; ++j) {
                    ax[i][j] = fmaf(xr[i], wxr[j], ax[i][j]);
                    ab[i][j] = fmaf(xr[i], wbr[j], ab[i][j]);
                    ac[i][j] = fmaf(xr[i], wcr[j], ac[i][j]);
                    ad[i][j] = fmaf(xr[i], wdr[j], ad[i][j]);
                }
            }
        }
    }

    // epilogue: bias + A/u/C, vectorized stores
    const int ng = n0 + tx * 4;
    float bxv[4], bbv[4], bcv[4], bdv[4];
    #pragma unroll
    for (int j = 0; j < 4; ++j) {
        bxv[j] = bx [ng + j];
        bbv[j] = bbc[ng + j];
        bcv[j] = bbc[NST + ng + j];
        bdv[j] = bd [ng + j];
    }
    #pragma unroll
    for (int i = 0; i < 4; ++i) {
        const int rg = row0 + ty * 4 + i;
        float av[4], uv[4], cv[4];
        #pragma unroll
        for (int j = 0; j < 4; ++j) {
            float xp = ax[i][j] + bxv[j];
            float bm = ab[i][j] + bbv[j];
            float cc = ac[i][j] + bcv[j];
            float dd = ad[i][j] + bdv[j];
            dd = fminf(dd, 60.0f);                 // overflow guard
            float e  = __expf(dd);
            float A  = 1.0f / (1.0f + e);          // exp(-softplus(d))
            av[j] = A;
            uv[j] = (e * A) * bm * xp;             // (1-A)*Bm*x_proj
            cv[j] = cc;
        }
        size_t base = (size_t)rg * NST + ng;
        *(float4*)&Aarr[base] = *(float4*)av;
        *(float4*)&Uarr[base] = *(float4*)uv;
        *(float4*)&Carr[base] = *(float4*)cv;
    }
}

// ---------------------------------------------------------------------------
// Kernel 2a: per-chunk local scan. One thread per (b, chunk, n).
// Produces chunk summary (prod A, h_end with h_in = 0).
// Note row = b*LSEQ + chunk*LC + t = bc*LC + t  where bc = b*NC + chunk.
// ---------------------------------------------------------------------------
__global__ __launch_bounds__(256)
void scan_local_kernel(const float* __restrict__ Aarr, const float* __restrict__ Uarr,
                       float* __restrict__ Aprod, float* __restrict__ Hend)
{
    const int gid = blockIdx.x * 256 + threadIdx.x;   // 0 .. BB*NC*NST-1
    const int n   = gid & (NST - 1);
    const int bc  = gid >> 9;                         // b*NC + chunk
    const float* Ap = Aarr + (size_t)bc * LC * NST + n;
    const float* Up = Uarr + (size_t)bc * LC * NST + n;
    float ap = 1.0f, h = 0.0f;
    #pragma unroll 8
    for (int t = 0; t < LC; ++t) {
        float a  = Ap[(size_t)t * NST];
        float uu = Up[(size_t)t * NST];
        ap *= a;
        h = fmaf(a, h, uu);
    }
    Aprod[(size_t)bc * NST + n] = ap;
    Hend [(size_t)bc * NST + n] = h;
}

// ---------------------------------------------------------------------------
// Kernel 2b: carry scan across chunks, per channel (b, n). Tiny (1 MB).
// Carry[b,chunk,n] = h entering that chunk.
// ---------------------------------------------------------------------------
__global__ __launch_bounds__(256)
void scan_carry_kernel(const float* __restrict__ Aprod, const float* __restrict__ Hend,
                       float* __restrict__ Carry)
{
    const int gid = blockIdx.x * 256 + threadIdx.x;   // 0 .. BB*NST-1
    const int n   = gid & (NST - 1);
    const int b   = gid >> 9;
    float h = 0.0f;
    for (int c = 0; c < NC; ++c) {
        size_t idx = ((size_t)(b * NC + c)) * NST + n;
        Carry[idx] = h;
        h = fmaf(Aprod[idx], h, Hend[idx]);
    }
}

// ---------------------------------------------------------------------------
// Kernel 2c: replay local scan with carry, write y = C*h in place over U.
// ---------------------------------------------------------------------------
__global__ __launch_bounds__(256)
void scan_final_kernel(const float* __restrict__ Aarr, float* __restrict__ Uarr,
                       const float* __restrict__ Carr, const float* __restrict__ Carry)
{
    const int gid = blockIdx.x * 256 + threadIdx.x;
    const int n   = gid & (NST - 1);
    const int bc  = gid >> 9;
    const size_t base = (size_t)bc * LC * NST + n;
    float h = Carry[(size_t)bc * NST + n];
    #pragma unroll 8
    for (int t = 0; t < LC; ++t) {
        size_t idx = base + (size_t)t * NST;
        float a  = Aarr[idx];
        float uu = Uarr[idx];
        float cc = Carr[idx];
        h = fmaf(a, h, uu);
        Uarr[idx] = cc * h;          // y overwrites u
    }
}

// ---------------------------------------------------------------------------
// Kernel 3: out = y @ Wy + by.  [ROWS,512]@[512,256].
// Same tiling scheme as proj_kernel, single matrix.
// ---------------------------------------------------------------------------
__global__ __launch_bounds__(256, 4)
void out_gemm_kernel(const float* __restrict__ Y, const float* __restrict__ Wy,
                     const float* __restrict__ by, float* __restrict__ out)
{
    constexpr int KT = 16;
    __shared__ alignas(16) float ys[KT][64];
    __shared__ alignas(16) float ws[KT][64];

    const int tid  = threadIdx.x;
    const int tx   = tid & 15;
    const int ty   = tid >> 4;
    const int row0 = blockIdx.x * 64;
    const int n0   = blockIdx.y * 64;

    float acc[4][4] = {{0}};

    const int lrow = tid >> 2;
    const int lkq  = tid & 3;
    const int wk   = tid >> 4;
    const int wn4  = tid & 15;

    for (int k0 = 0; k0 < NST; k0 += KT) {
        float4 yv = *(const float4*)&Y [(size_t)(row0 + lrow) * NST + k0 + lkq * 4];
        float4 wv = *(const float4*)&Wy[(size_t)(k0 + wk) * COUT    + n0 + wn4 * 4];
        __syncthreads();
        ys[lkq*4 + 0][lrow] = yv.x;
        ys[lkq*4 + 1][lrow] = yv.y;
        ys[lkq*4 + 2][lrow] = yv.z;
        ys[lkq*4 + 3][lrow] = yv.w;
        *(float4*)&ws[wk][wn4*4] = wv;
        __syncthreads();

        #pragma unroll
        for (int kk = 0; kk < KT; ++kk) {
            float yr[4], wr[4];
            *(float4*)yr = *(const float4*)&ys[kk][ty*4];
            *(float4*)wr = *(const float4*)&ws[kk][tx*4];
            #pragma unroll
            for (int i = 0; i < 4; ++i)
                #pragma unroll
                for (int j = 0; j < 4; ++j)
                    acc[i][j] = fmaf(yr[i], wr[j], acc[i][j]);
        }
    }

    const int ng = n0 + tx * 4;
    float bv[4];
    #pragma unroll
    for (int j = 0; j < 4; ++j) bv[j] = by[ng + j];
    #pragma unroll
    for (int i = 0; i < 4; ++i) {
        const int rg = row0 + ty * 4 + i;
        float ov[4];
        #pragma unroll
        for (int j = 0; j < 4; ++j) ov[j] = acc[i][j] + bv[j];
        *(float4*)&out[(size_t)rg * COUT + ng] = *(float4*)ov;
    }
}

// ---------------------------------------------------------------------------
// Workspace layout (fp32 elements):
//   Aarr  : ROWS*NST            (33.55 MB)
//   Uarr  : ROWS*NST            (33.55 MB)  -- y overwrites this in scan_final
//   Carr  : ROWS*NST            (33.55 MB)
//   Aprod : BB*NC*NST           (0.52 MB)
//   Hend  : BB*NC*NST           (0.52 MB)
//   Carry : BB*NC*NST           (0.52 MB)
// Total ~102.2 MB.
// ---------------------------------------------------------------------------
extern "C" void kernel_launch(void* const* d_in, const int* in_sizes, int n_in,
                              void* d_out, int out_size, void* d_ws, size_t ws_size,
                              hipStream_t stream)
{
    const float* x   = (const float*)d_in[0];
    const float* Wx  = (const float*)d_in[1];
    const float* bx  = (const float*)d_in[2];
    const float* Wbc = (const float*)d_in[3];
    const float* bbc = (const float*)d_in[4];
    const float* Wd  = (const float*)d_in[5];
    const float* bd  = (const float*)d_in[6];
    const float* Wy  = (const float*)d_in[7];
    const float* by  = (const float*)d_in[8];
    float* out = (float*)d_out;

    float* Aarr  = (float*)d_ws;
    float* Uarr  = Aarr  + (size_t)ROWS * NST;
    float* Carr  = Uarr  + (size_t)ROWS * NST;
    float* Aprod = Carr  + (size_t)ROWS * NST;
    float* Hend  = Aprod + (size_t)BB * NC * NST;
    float* Carry = Hend  + (size_t)BB * NC * NST;

    proj_kernel<<<dim3(ROWS / 64, NST / 64), 256, 0, stream>>>(
        x, Wx, bx, Wbc, bbc, Wd, bd, Aarr, Uarr, Carr);

    scan_local_kernel<<<(BB * NC * NST) / 256, 256, 0, stream>>>(
        Aarr, Uarr, Aprod, Hend);

    scan_carry_kernel<<<(BB * NST) / 256, 256, 0, stream>>>(
        Aprod, Hend, Carry);

    scan_final_kernel<<<(BB * NC * NST) / 256, 256, 0, stream>>>(
        Aarr, Uarr, Carr, Carry);

    out_gemm_kernel<<<dim3(ROWS / 64, COUT / 64), 256, 0, stream>>>(
        Uarr, Wy, by, out);
}

// Round 2
// 162.225 us; speedup vs baseline: 2.3794x; 2.3794x over previous
//
#include <hip/hip_runtime.h>
#include <math.h>

// Problem constants (fixed by reference setup_inputs)
constexpr int CIN  = 256;
constexpr int NST  = 512;          // N
constexpr int LSEQ = 4096;
constexpr int BB   = 4;
constexpr int ROWS = BB * LSEQ;    // 16384
constexpr int COUT = 256;
constexpr int LC   = 64;           // scan chunk length
constexpr int NC   = LSEQ / LC;    // 64 chunks per batch

typedef __attribute__((ext_vector_type(8))) short bf16x8;
typedef __attribute__((ext_vector_type(4))) float f32x4;
typedef unsigned short ushort_t;
typedef unsigned int   uint_t;

__device__ __forceinline__ ushort_t f2bf(float f) {
    uint_t u = __float_as_uint(f);
    u = (u + 0x7FFF + ((u >> 16) & 1)) >> 16;   // RNE
    return (ushort_t)u;
}
__device__ __forceinline__ float bf2f(ushort_t s) {
    return __uint_as_float(((uint_t)s) << 16);
}

// ---------------------------------------------------------------------------
// prep_w: convert weights to bf16, TRANSPOSED to [n][k] (k contiguous) so MFMA
// B-fragments are 16B-contiguous reads.
//   Wt [4][NST][CIN]  : mats {0:Wx, 1:Wbc[:, :N], 2:Wbc[:, N:], 3:Wd}
//   Wyt[COUT][NST]
// ---------------------------------------------------------------------------
__global__ __launch_bounds__(256)
void prep_w_kernel(const float* __restrict__ Wx, const float* __restrict__ Wbc,
                   const float* __restrict__ Wd, const float* __restrict__ Wy,
                   ushort_t* __restrict__ Wt, ushort_t* __restrict__ Wyt)
{
    const int gid = blockIdx.x * 256 + threadIdx.x;
    if (gid < 4 * NST * CIN) {
        const int mat = gid >> 17;            // 512*256 = 131072 per mat
        const int idx = gid & 131071;
        const int k   = idx >> 9;             // 0..255
        const int n   = idx & 511;            // 0..511 (coalesced reads)
        float v;
        if      (mat == 0) v = Wx [k * NST + n];
        else if (mat == 1) v = Wbc[k * (2 * NST) + n];
        else if (mat == 2) v = Wbc[k * (2 * NST) + NST + n];
        else               v = Wd [k * NST + n];
        Wt[((size_t)mat * NST + n) * CIN + k] = f2bf(v);
    } else {
        const int idx = gid - 4 * NST * CIN;  // 0 .. 512*256-1
        const int k   = idx >> 8;             // 0..511
        const int n   = idx & 255;            // 0..255
        Wyt[(size_t)n * NST + k] = f2bf(Wy[k * COUT + n]);
    }
}

// ---------------------------------------------------------------------------
// prep_x: x fp32 -> bf16 (row-major, k contiguous)
// ---------------------------------------------------------------------------
__global__ __launch_bounds__(256)
void prep_x_kernel(const float* __restrict__ x, ushort_t* __restrict__ xb)
{
    const int i = (blockIdx.x * 256 + threadIdx.x) * 4;
    float4 v = *(const float4*)&x[i];
    uint2 o;
    o.x = (uint_t)f2bf(v.x) | ((uint_t)f2bf(v.y) << 16);
    o.y = (uint_t)f2bf(v.z) | ((uint_t)f2bf(v.w) << 16);
    *(uint2*)&xb[i] = o;
}

// ---------------------------------------------------------------------------
// proj_mfma: fused 4-matrix projection GEMM via 16x16x32 bf16 MFMA + epilogue.
// Tile: 64 rows x 64 n x 4 mats. 4 waves; wave w owns n-slice [w*16, w*16+16)
// for ALL 4 matrices -> epilogue (A, u, Cbf16) is in-lane, no LDS roundtrip.
// A-frag: lane holds A[m=lane&15][k=(lane>>4)*8+j] -> xs row-major k-contig.
// B-frag: lane holds B[k=(lane>>4)*8+j][n=lane&15] -> ws = W^T, k-contig.
// C/D:    col(n)=lane&15, row=(lane>>4)*4+reg.
// LDS pad +8 bf16 (stride 72) -> only 2-way bank aliasing (free).
// ---------------------------------------------------------------------------
__global__ __launch_bounds__(256, 3)
void proj_mfma_kernel(const ushort_t* __restrict__ xb, const ushort_t* __restrict__ Wt,
                      const float* __restrict__ bx, const float* __restrict__ bbc,
                      const float* __restrict__ bd,
                      float* __restrict__ Aarr, float* __restrict__ Uarr,
                      ushort_t* __restrict__ CYb)
{
    __shared__ alignas(16) ushort_t xs[64][72];
    __shared__ alignas(16) ushort_t ws[4][64][72];

    const int tid  = threadIdx.x;
    const int wave = tid >> 6;
    const int lane = tid & 63;
    const int lm   = lane & 15;       // 16-dim index (row for A, n for B/D)
    const int lq   = lane >> 4;       // k-quad / row-quad
    const int row0 = blockIdx.x * 64;
    const int n0   = blockIdx.y * 64;

    // staging assignment: thread t -> row/n = t>>2, k-quad16 = (t&3)*16
    const int sr = tid >> 2;
    const int sk = (tid & 3) << 4;

    f32x4 acc[4][4];                  // [rowtile][mat]
    #pragma unroll
    for (int rt = 0; rt < 4; ++rt)
        #pragma unroll
        for (int m = 0; m < 4; ++m)
            acc[rt][m] = (f32x4){0.f, 0.f, 0.f, 0.f};

    const ushort_t* xsrc = xb + (size_t)(row0 + sr) * CIN + sk;
    const ushort_t* wsrc0 = Wt + (size_t)(n0 + sr) * CIN + sk;                 // mat stride = NST*CIN

    for (int k0 = 0; k0 < CIN; k0 += 64) {
        // stage x tile and 4 W tiles (bf16, 2x16B per thread per tile)
        uint4 xv0 = *(const uint4*)(xsrc + k0);
        uint4 xv1 = *(const uint4*)(xsrc + k0 + 8);
        uint4 wv[4][2];
        #pragma unroll
        for (int m = 0; m < 4; ++m) {
            const ushort_t* p = wsrc0 + (size_t)m * NST * CIN + k0;
            wv[m][0] = *(const uint4*)(p);
            wv[m][1] = *(const uint4*)(p + 8);
        }
        *(uint4*)&xs[sr][sk]     = xv0;
        *(uint4*)&xs[sr][sk + 8] = xv1;
        #pragma unroll
        for (int m = 0; m < 4; ++m) {
            *(uint4*)&ws[m][sr][sk]     = wv[m][0];
            *(uint4*)&ws[m][sr][sk + 8] = wv[m][1];
        }
        __syncthreads();

        #pragma unroll
        for (int ks = 0; ks < 2; ++ks) {
            const int kk = ks * 32 + lq * 8;
            bf16x8 af[4], bf[4];
            #pragma unroll
            for (int rt = 0; rt < 4; ++rt)
                af[rt] = *(const bf16x8*)&xs[rt * 16 + lm][kk];
            #pragma unroll
            for (int m = 0; m < 4; ++m)
                bf[m] = *(const bf16x8*)&ws[m][wave * 16 + lm][kk];
            #pragma unroll
            for (int rt = 0; rt < 4; ++rt)
                #pragma unroll
                for (int m = 0; m < 4; ++m)
                    acc[rt][m] = __builtin_amdgcn_mfma_f32_16x16x32_bf16(
                        af[rt], bf[m], acc[rt][m], 0, 0, 0);
        }
        __syncthreads();
    }

    // epilogue: in-lane, n fixed per lane
    const int ng = n0 + wave * 16 + lm;
    const float bxv = bx [ng];
    const float bbv = bbc[ng];
    const float bcv = bbc[NST + ng];
    const float bdv = bd [ng];
    #pragma unroll
    for (int rt = 0; rt < 4; ++rt) {
        #pragma unroll
        for (int r = 0; r < 4; ++r) {
            const int row = row0 + rt * 16 + lq * 4 + r;
            float xp = acc[rt][0][r] + bxv;
            float bm = acc[rt][1][r] + bbv;
            float cc = acc[rt][2][r] + bcv;
            float dd = acc[rt][3][r] + bdv;
            dd = fminf(dd, 60.0f);
            float e  = __expf(dd);
            float A  = 1.0f / (1.0f + e);        // exp(-softplus(d))
            float u  = (e * A) * bm * xp;        // (1-A)*Bm*x_proj
            const size_t idx = (size_t)row * NST + ng;
            Aarr[idx] = A;
            Uarr[idx] = u;
            CYb[idx]  = f2bf(cc);
        }
    }
}

// ---------------------------------------------------------------------------
// scan kernels (chunked associative scan), A/u fp32; C/y bf16 in-place.
// ---------------------------------------------------------------------------
__global__ __launch_bounds__(256)
void scan_local_kernel(const float* __restrict__ Aarr, const float* __restrict__ Uarr,
                       float* __restrict__ Aprod, float* __restrict__ Hend)
{
    const int gid = blockIdx.x * 256 + threadIdx.x;   // 0 .. BB*NC*NST-1
    const int n   = gid & (NST - 1);
    const int bc  = gid >> 9;
    const float* Ap = Aarr + (size_t)bc * LC * NST + n;
    const float* Up = Uarr + (size_t)bc * LC * NST + n;
    float ap = 1.0f, h = 0.0f;
    #pragma unroll 8
    for (int t = 0; t < LC; ++t) {
        float a  = Ap[(size_t)t * NST];
        float uu = Up[(size_t)t * NST];
        ap *= a;
        h = fmaf(a, h, uu);
    }
    Aprod[(size_t)bc * NST + n] = ap;
    Hend [(size_t)bc * NST + n] = h;
}

__global__ __launch_bounds__(256)
void scan_carry_kernel(const float* __restrict__ Aprod, const float* __restrict__ Hend,
                       float* __restrict__ Carry)
{
    const int gid = blockIdx.x * 256 + threadIdx.x;   // 0 .. BB*NST-1
    const int n   = gid & (NST - 1);
    const int b   = gid >> 9;
    float h = 0.0f;
    for (int c = 0; c < NC; ++c) {
        size_t idx = ((size_t)(b * NC + c)) * NST + n;
        Carry[idx] = h;
        h = fmaf(Aprod[idx], h, Hend[idx]);
    }
}

__global__ __launch_bounds__(256)
void scan_final_kernel(const float* __restrict__ Aarr, const float* __restrict__ Uarr,
                       ushort_t* __restrict__ CYb, const float* __restrict__ Carry)
{
    const int gid = blockIdx.x * 256 + threadIdx.x;
    const int n   = gid & (NST - 1);
    const int bc  = gid >> 9;
    const size_t base = (size_t)bc * LC * NST + n;
    float h = Carry[(size_t)bc * NST + n];
    #pragma unroll 8
    for (int t = 0; t < LC; ++t) {
        size_t idx = base + (size_t)t * NST;
        float a  = Aarr[idx];
        float uu = Uarr[idx];
        float cc = bf2f(CYb[idx]);
        h = fmaf(a, h, uu);
        CYb[idx] = f2bf(cc * h);     // y overwrites C (same slot, same thread)
    }
}

// ---------------------------------------------------------------------------
// out_mfma: out = y @ Wy + by via 16x16x32 bf16 MFMA. Tile 64 rows x 64 cols.
// ---------------------------------------------------------------------------
__global__ __launch_bounds__(256, 4)
void out_mfma_kernel(const ushort_t* __restrict__ yb, const ushort_t* __restrict__ Wyt,
                     const float* __restrict__ by, float* __restrict__ out)
{
    __shared__ alignas(16) ushort_t ys [64][72];
    __shared__ alignas(16) ushort_t wys[64][72];

    const int tid  = threadIdx.x;
    const int wave = tid >> 6;
    const int lane = tid & 63;
    const int lm   = lane & 15;
    const int lq   = lane >> 4;
    const int row0 = blockIdx.x * 64;
    const int n0   = blockIdx.y * 64;

    const int sr = tid >> 2;
    const int sk = (tid & 3) << 4;

    f32x4 acc[4];
    #pragma unroll
    for (int rt = 0; rt < 4; ++rt) acc[rt] = (f32x4){0.f, 0.f, 0.f, 0.f};

    const ushort_t* ysrc = yb  + (size_t)(row0 + sr) * NST + sk;
    const ushort_t* wsrc = Wyt + (size_t)(n0  + sr) * NST + sk;

    for (int k0 = 0; k0 < NST; k0 += 64) {
        uint4 yv0 = *(const uint4*)(ysrc + k0);
        uint4 yv1 = *(const uint4*)(ysrc + k0 + 8);
        uint4 wv0 = *(const uint4*)(wsrc + k0);
        uint4 wv1 = *(const uint4*)(wsrc + k0 + 8);
        *(uint4*)&ys [sr][sk]     = yv0;
        *(uint4*)&ys [sr][sk + 8] = yv1;
        *(uint4*)&wys[sr][sk]     = wv0;
        *(uint4*)&wys[sr][sk + 8] = wv1;
        __syncthreads();

        #pragma unroll
        for (int ks = 0; ks < 2; ++ks) {
            const int kk = ks * 32 + lq * 8;
            bf16x8 bfr = *(const bf16x8*)&wys[wave * 16 + lm][kk];
            #pragma unroll
            for (int rt = 0; rt < 4; ++rt) {
                bf16x8 af = *(const bf16x8*)&ys[rt * 16 + lm][kk];
                acc[rt] = __builtin_amdgcn_mfma_f32_16x16x32_bf16(
                    af, bfr, acc[rt], 0, 0, 0);
            }
        }
        __syncthreads();
    }

    const int ng = n0 + wave * 16 + lm;
    const float bv = by[ng];
    #pragma unroll
    for (int rt = 0; rt < 4; ++rt)
        #pragma unroll
        for (int r = 0; r < 4; ++r) {
            const int row = row0 + rt * 16 + lq * 4 + r;
            out[(size_t)row * COUT + ng] = acc[rt][r] + bv;
        }
}

// ---------------------------------------------------------------------------
// Workspace layout (bytes, all 16B aligned):
//   Aarr  fp32   ROWS*NST    33,554,432
//   Uarr  fp32   ROWS*NST    33,554,432
//   CYb   bf16   ROWS*NST    16,777,216   (C from proj; y in-place after scan)
//   xb    bf16   ROWS*CIN     8,388,608
//   Wt    bf16   4*NST*CIN    1,048,576
//   Wyt   bf16   COUT*NST       262,144
//   Aprod fp32   BB*NC*NST      524,288
//   Hend  fp32   BB*NC*NST      524,288
//   Carry fp32   BB*NC*NST      524,288
// total 95,158,272 B (< 102.2 MB proven available in round 1)
// ---------------------------------------------------------------------------
extern "C" void kernel_launch(void* const* d_in, const int* in_sizes, int n_in,
                              void* d_out, int out_size, void* d_ws, size_t ws_size,
                              hipStream_t stream)
{
    const float* x   = (const float*)d_in[0];
    const float* Wx  = (const float*)d_in[1];
    const float* bx  = (const float*)d_in[2];
    const float* Wbc = (const float*)d_in[3];
    const float* bbc = (const float*)d_in[4];
    const float* Wd  = (const float*)d_in[5];
    const float* bd  = (const float*)d_in[6];
    const float* Wy  = (const float*)d_in[7];
    const float* by  = (const float*)d_in[8];
    float* out = (float*)d_out;

    char* p = (char*)d_ws;
    float*    Aarr  = (float*)p;          p += (size_t)ROWS * NST * 4;
    float*    Uarr  = (float*)p;          p += (size_t)ROWS * NST * 4;
    ushort_t* CYb   = (ushort_t*)p;       p += (size_t)ROWS * NST * 2;
    ushort_t* xb    = (ushort_t*)p;       p += (size_t)ROWS * CIN * 2;
    ushort_t* Wt    = (ushort_t*)p;       p += (size_t)4 * NST * CIN * 2;
    ushort_t* Wyt   = (ushort_t*)p;       p += (size_t)COUT * NST * 2;
    float*    Aprod = (float*)p;          p += (size_t)BB * NC * NST * 4;
    float*    Hend  = (float*)p;          p += (size_t)BB * NC * NST * 4;
    float*    Carry = (float*)p;          p += (size_t)BB * NC * NST * 4;

    prep_w_kernel<<<(4 * NST * CIN + COUT * NST) / 256, 256, 0, stream>>>(
        Wx, Wbc, Wd, Wy, Wt, Wyt);

    prep_x_kernel<<<(ROWS * CIN / 4) / 256, 256, 0, stream>>>(x, xb);

    proj_mfma_kernel<<<dim3(ROWS / 64, NST / 64), 256, 0, stream>>>(
        xb, Wt, bx, bbc, bd, Aarr, Uarr, CYb);

    scan_local_kernel<<<(BB * NC * NST) / 256, 256, 0, stream>>>(
        Aarr, Uarr, Aprod, Hend);

    scan_carry_kernel<<<(BB * NST) / 256, 256, 0, stream>>>(
        Aprod, Hend, Carry);

    scan_final_kernel<<<(BB * NC * NST) / 256, 256, 0, stream>>>(
        Aarr, Uarr, CYb, Carry);

    out_mfma_kernel<<<dim3(ROWS / 64, COUT / 64), 256, 0, stream>>>(
        CYb, Wyt, by, out);
}